// Round 6
// baseline (282.738 us; speedup 1.0000x reference)
//
#include <hip/hip_runtime.h>
#include <hip/hip_bf16.h>
#include <hip/hip_cooperative_groups.h>

namespace cg = cooperative_groups;

#define N_ROWS 8192
#define T_STEPS 60
#define DFEAT 6

typedef _Float16 f16x8 __attribute__((ext_vector_type(8)));
typedef float f32x4 __attribute__((ext_vector_type(4)));
typedef float fvec4 __attribute__((ext_vector_type(4)));

#if __has_builtin(__builtin_amdgcn_exp2f)
#define EXP2F(x) __builtin_amdgcn_exp2f(x)
#else
#define EXP2F(x) exp2f(x)
#endif
#define RCPF(x) __builtin_amdgcn_rcpf(x)

#define LOG2E  1.4426950408889634f
#define LOG2E2 2.8853900817779268f

#define MFMA16(a, b, c) __builtin_amdgcn_mfma_f32_16x16x32_f16(a, b, c, 0, 0, 0)

// Load 8 consecutive fp32 weights W[(g*64+jcol)][kf*32+rowgrp*8 .. +8), scale
// by SC (log2e folding), as fp16 B-frag (col=lane&15, k=(lane>>4)*8+e).
#define LOAD_WS(W, g, kf, SC, DST) do {                                       \
    const float* _p = (W) + ((g)*64 + jcol)*64 + (kf)*32 + rowgrp*8;          \
    fvec4 _v0 = *(const fvec4*)_p;                                            \
    fvec4 _v1 = *(const fvec4*)(_p + 4);                                      \
    f16x8 _f;                                                                 \
    _Pragma("unroll")                                                         \
    for (int _e = 0; _e < 4; ++_e) {                                          \
        _f[_e]     = (_Float16)(_v0[_e] * (SC));                              \
        _f[4 + _e] = (_Float16)(_v1[_e] * (SC));                              \
    }                                                                         \
    DST = _f;                                                                 \
} while (0)

__device__ __forceinline__ int hswz(int row, int col) {
    return row * 64 + (col ^ ((row & 7) << 3));
}

// Persistent MFMA GRU, layer-pipelined across wave roles.
// 512 blocks x 512 threads (8 waves). Block owns 16 rows.
// Waves 0-3 (role A): layer 0 at step tt.  Waves 4-7 (role B): layer 1 at
// step tt-1.  One barrier per iteration (61 total vs 120).
// 16 waves/CU = 4 waves/SIMD.  Weights fp16 in regs, pre-scaled by log2e
// (r,z) / 2log2e (n) so gates need only v_exp+v_rcp.
__global__ __launch_bounds__(512, 4)
void gru_fused(const float* __restrict__ x,
               const float* __restrict__ Wih0, const float* __restrict__ Whh0,
               const float* __restrict__ bih0, const float* __restrict__ bhh0,
               const float* __restrict__ Wih1, const float* __restrict__ Whh1,
               const float* __restrict__ bih1, const float* __restrict__ bhh1,
               float* __restrict__ hidden)
{
    __shared__ __align__(16) _Float16 h0s[2][1024];   // [buf][swizzled 16x64]
    __shared__ __align__(16) _Float16 h1s[2][1024];
    __shared__ __align__(16) _Float16 xs[T_STEPS][16][8];
    __shared__ __align__(16) _Float16 zx[8];

    const int tid = threadIdx.x;
    const int lane = tid & 63;
    const int wv = tid >> 6;          // 0..7
    const int roleB = wv >> 2;        // 0: layer0, 1: layer1
    const int cg_ = wv & 3;
    const int lrow = lane & 15;
    const int rowgrp = lane >> 4;
    const int jcol = cg_ * 16 + lrow;
    const int rbase = blockIdx.x * 16;

    for (int i = tid; i < 1024; i += 512) {
        h0s[0][i] = (_Float16)0.f; h0s[1][i] = (_Float16)0.f;
        h1s[0][i] = (_Float16)0.f; h1s[1][i] = (_Float16)0.f;
    }
    if (tid < 8) zx[tid] = (_Float16)0.f;
    for (int idx = tid; idx < 16 * T_STEPS; idx += 512) {
        int t = idx >> 4, r = idx & 15;
        const float* xp = x + (long)(rbase + r) * (DFEAT * T_STEPS) + t;
        f16x8 f;
#pragma unroll
        for (int d = 0; d < DFEAT; ++d) f[d] = (_Float16)xp[d * T_STEPS];
        f[6] = (_Float16)0.f; f[7] = (_Float16)0.f;
        *(f16x8*)&xs[t][r][0] = f;
    }

    f16x8 zerof;
#pragma unroll
    for (int e = 0; e < 8; ++e) zerof[e] = (_Float16)0.f;

    // role-dependent weight fragments (all indices compile-time)
    f16x8 wg[12];
#pragma unroll
    for (int i = 0; i < 12; ++i) wg[i] = zerof;
    float br, bz, bxn, bhn;
    if (roleB == 0) {
        LOAD_WS(Whh0, 0, 0, LOG2E,  wg[0]);  LOAD_WS(Whh0, 0, 1, LOG2E,  wg[1]);
        LOAD_WS(Whh0, 1, 0, LOG2E,  wg[2]);  LOAD_WS(Whh0, 1, 1, LOG2E,  wg[3]);
        LOAD_WS(Whh0, 2, 0, LOG2E2, wg[4]);  LOAD_WS(Whh0, 2, 1, LOG2E2, wg[5]);
        if (rowgrp == 0) {
#pragma unroll
            for (int g = 0; g < 3; ++g) {
                const float sc = (g == 2) ? LOG2E2 : LOG2E;
                f16x8 f = zerof;
#pragma unroll
                for (int e = 0; e < DFEAT; ++e)
                    f[e] = (_Float16)(Wih0[(g * 64 + jcol) * DFEAT + e] * sc);
                wg[6 + g] = f;
            }
        }
        br  = (bih0[jcol] + bhh0[jcol]) * LOG2E;
        bz  = (bih0[64 + jcol] + bhh0[64 + jcol]) * LOG2E;
        bxn = bih0[128 + jcol] * LOG2E2;
        bhn = bhh0[128 + jcol] * LOG2E2;
    } else {
        LOAD_WS(Wih1, 0, 0, LOG2E,  wg[0]);  LOAD_WS(Wih1, 0, 1, LOG2E,  wg[1]);
        LOAD_WS(Wih1, 1, 0, LOG2E,  wg[2]);  LOAD_WS(Wih1, 1, 1, LOG2E,  wg[3]);
        LOAD_WS(Wih1, 2, 0, LOG2E2, wg[4]);  LOAD_WS(Wih1, 2, 1, LOG2E2, wg[5]);
        LOAD_WS(Whh1, 0, 0, LOG2E,  wg[6]);  LOAD_WS(Whh1, 0, 1, LOG2E,  wg[7]);
        LOAD_WS(Whh1, 1, 0, LOG2E,  wg[8]);  LOAD_WS(Whh1, 1, 1, LOG2E,  wg[9]);
        LOAD_WS(Whh1, 2, 0, LOG2E2, wg[10]); LOAD_WS(Whh1, 2, 1, LOG2E2, wg[11]);
        br  = (bih1[jcol] + bhh1[jcol]) * LOG2E;
        bz  = (bih1[64 + jcol] + bhh1[64 + jcol]) * LOG2E;
        bxn = bih1[128 + jcol] * LOG2E2;
        bhn = bhh1[128 + jcol] * LOG2E2;
    }

    float hreg[4] = {0.f, 0.f, 0.f, 0.f};

    const _Float16* xbase_l = (rowgrp == 0) ? &xs[0][lrow][0] : &zx[0];
    const long xinc = (rowgrp == 0) ? 128 : 0;

    int widx[4];
#pragma unroll
    for (int q = 0; q < 4; ++q) widx[q] = hswz(rowgrp * 4 + q, jcol);
    const int ridx0 = lrow * 64 + ((rowgrp * 8) ^ ((lrow & 7) << 3));
    const int ridx1 = lrow * 64 + ((32 + rowgrp * 8) ^ ((lrow & 7) << 3));

    __syncthreads();

#pragma unroll 1
    for (int tt = 0; tt <= T_STEPS; ++tt) {
        if (roleB == 0) {
            if (tt < T_STEPS) {
                const int rb = (tt + 1) & 1;     // h0(tt-1)
                f16x8 hf0 = *(const f16x8*)&h0s[rb][ridx0];
                f16x8 hf1 = *(const f16x8*)&h0s[rb][ridx1];
                f16x8 xf  = *(const f16x8*)(xbase_l + (long)tt * xinc);
                f32x4 accr  = {br, br, br, br};
                f32x4 accz  = {bz, bz, bz, bz};
                f32x4 accxn = {bxn, bxn, bxn, bxn};
                f32x4 acchn = {bhn, bhn, bhn, bhn};
                accr  = MFMA16(xf,  wg[6], accr);
                accr  = MFMA16(hf0, wg[0], accr);
                accr  = MFMA16(hf1, wg[1], accr);
                accz  = MFMA16(xf,  wg[7], accz);
                accz  = MFMA16(hf0, wg[2], accz);
                accz  = MFMA16(hf1, wg[3], accz);
                accxn = MFMA16(xf,  wg[8], accxn);
                acchn = MFMA16(hf0, wg[4], acchn);
                acchn = MFMA16(hf1, wg[5], acchn);
#pragma unroll
                for (int q = 0; q < 4; ++q) {
                    float r = RCPF(1.0f + EXP2F(-accr[q]));
                    float z = RCPF(1.0f + EXP2F(-accz[q]));
                    float v = accxn[q] + r * acchn[q];
                    float n = 2.0f * RCPF(1.0f + EXP2F(-v)) - 1.0f;
                    hreg[q] = n + z * (hreg[q] - n);
                }
                const int wb = tt & 1;
#pragma unroll
                for (int q = 0; q < 4; ++q)
                    h0s[wb][widx[q]] = (_Float16)hreg[q];
            }
        } else {
            if (tt > 0) {
                const int rb0 = (tt + 1) & 1;    // h0(tt-1)
                const int rb1 = tt & 1;          // h1(tt-2)
                f16x8 xf0 = *(const f16x8*)&h0s[rb0][ridx0];
                f16x8 xf1 = *(const f16x8*)&h0s[rb0][ridx1];
                f16x8 hf0 = *(const f16x8*)&h1s[rb1][ridx0];
                f16x8 hf1 = *(const f16x8*)&h1s[rb1][ridx1];
                f32x4 accr  = {br, br, br, br};
                f32x4 accz  = {bz, bz, bz, bz};
                f32x4 accxn = {bxn, bxn, bxn, bxn};
                f32x4 acchn = {bhn, bhn, bhn, bhn};
                accr  = MFMA16(xf0, wg[0], accr);
                accr  = MFMA16(xf1, wg[1], accr);
                accr  = MFMA16(hf0, wg[6], accr);
                accr  = MFMA16(hf1, wg[7], accr);
                accz  = MFMA16(xf0, wg[2], accz);
                accz  = MFMA16(xf1, wg[3], accz);
                accz  = MFMA16(hf0, wg[8], accz);
                accz  = MFMA16(hf1, wg[9], accz);
                accxn = MFMA16(xf0, wg[4], accxn);
                accxn = MFMA16(xf1, wg[5], accxn);
                acchn = MFMA16(hf0, wg[10], acchn);
                acchn = MFMA16(hf1, wg[11], acchn);
#pragma unroll
                for (int q = 0; q < 4; ++q) {
                    float r = RCPF(1.0f + EXP2F(-accr[q]));
                    float z = RCPF(1.0f + EXP2F(-accz[q]));
                    float v = accxn[q] + r * acchn[q];
                    float n = 2.0f * RCPF(1.0f + EXP2F(-v)) - 1.0f;
                    hreg[q] = n + z * (hreg[q] - n);
                }
                const int wb = (tt + 1) & 1;     // h1(tt-1)
#pragma unroll
                for (int q = 0; q < 4; ++q)
                    h1s[wb][widx[q]] = (_Float16)hreg[q];
            }
        }
        __syncthreads();
    }

    if (roleB == 1) {
#pragma unroll
        for (int q = 0; q < 4; ++q)
            hidden[(long)(rbase + rowgrp * 4 + q) * 64 + jcol] = hreg[q];
    }
}

// Entire tail in ONE cooperative kernel (64 blocks x 256 thr, 4 grid syncs):
//  ph0: tile load + per-block BN1 column partials
//  ph1: bn1 coeffs -> hbn in LDS -> el, G/s/E2 partials (no atomics)
//  ph2: block k reduces G row k, computes M row k; misc reductions
//  ph3: GM row k -> A/B/bM atomic partials; sv
//  ph4: analytic BN2 coeffs + final matvec+lrelu+dot -> y
__global__ __launch_bounds__(256, 1)
void tail_kernel(const float* __restrict__ hidden,
                 const float* __restrict__ bn1w, const float* __restrict__ bn1b,
                 const float* __restrict__ fcw,  const float* __restrict__ fcb,
                 const float* __restrict__ bn2w, const float* __restrict__ bn2b,
                 const float* __restrict__ fow,  const float* __restrict__ fob,
                 float* __restrict__ y, float* wsb)
{
    float* csp    = wsb;              // [64][64]
    float* cqp    = wsb + 4096;       // [64][64]
    float* spart  = wsb + 8192;       // [64][64]
    float* e2part = wsb + 12288;      // [64]
    float* sred   = wsb + 12352;      // [64]
    float* E2g    = wsb + 12416;      // [1]
    float* Ag     = wsb + 12480;      // [64]
    float* Bg     = wsb + 12544;      // [64]
    float* bMg    = wsb + 12608;      // [64]
    float* svg    = wsb + 12672;      // [64]
    float* Mg     = wsb + 12736;      // [64][64]
    float* Gpart  = wsb + 16832;      // [64][64][64]

    __shared__ float tile[128][65];
    __shared__ float el[128];
    __shared__ float Fs[64][65];
    __shared__ float Msh[64][65];
    __shared__ float a1s[64], c1s[64], a2s[64], c2s[64];
    __shared__ float svs[64], fcs[64], wos[64];
    __shared__ float Grow[64];
    __shared__ float r4a[4][64], r4b[4][64];

    const int b = blockIdx.x, tid = threadIdx.x;
    cg::grid_group grid = cg::this_grid();

    // ---- phase 0 ----
    for (int i = tid; i < 8192; i += 256)
        tile[i >> 6][i & 63] = hidden[b * 8192 + i];
    for (int i = tid; i < 4096; i += 256)
        Fs[i >> 6][i & 63] = fcw[i];
    __syncthreads();
    {
        const int c = tid & 63, g = tid >> 6;
        float s = 0.f, q = 0.f;
        for (int r = g * 32; r < g * 32 + 32; ++r) {
            float v = tile[r][c]; s += v; q += v * v;
        }
        r4a[g][c] = s; r4b[g][c] = q;
    }
    __syncthreads();
    if (tid < 64) {
        csp[b * 64 + tid] = r4a[0][tid] + r4a[1][tid] + r4a[2][tid] + r4a[3][tid];
        cqp[b * 64 + tid] = r4b[0][tid] + r4b[1][tid] + r4b[2][tid] + r4b[3][tid];
    }
    __threadfence();
    grid.sync();

    // ---- phase 1 ----
    if (tid < 64) {
        float s = 0.f, q = 0.f;
        for (int bb = 0; bb < 64; ++bb) { s += csp[bb * 64 + tid]; q += cqp[bb * 64 + tid]; }
        float m = s * (1.0f / N_ROWS);
        float v = q * (1.0f / N_ROWS) - m * m;
        float a = bn1w[tid] * rsqrtf(v + 1e-5f);
        a1s[tid] = a; c1s[tid] = bn1b[tid] - m * a;
    }
    __syncthreads();
    for (int i = tid; i < 8192; i += 256) {
        int r = i >> 6, c = i & 63;
        tile[r][c] = tile[r][c] * a1s[c] + c1s[c];
    }
    __syncthreads();
    for (int r = tid; r < 128; r += 256) {
        float s = 0.f;
#pragma unroll 8
        for (int c = 0; c < 64; ++c) s += tile[r][c];
        el[r] = s * (1.0f / 64.0f);
    }
    __syncthreads();
    {
        const int j = tid & 63, kg = tid >> 6;
        float accG[16];
#pragma unroll
        for (int q = 0; q < 16; ++q) accG[q] = 0.f;
        for (int r = 0; r < 128; ++r) {
            float hj = tile[r][j];
#pragma unroll
            for (int q = 0; q < 16; ++q) accG[q] += tile[r][kg * 16 + q] * hj;
        }
#pragma unroll
        for (int q = 0; q < 16; ++q)
            Gpart[(b * 64 + kg * 16 + q) * 64 + j] = accG[q];
    }
    if (tid < 64) {
        float accS = 0.f;
        for (int r = 0; r < 128; ++r) accS += el[r] * tile[r][tid];
        spart[b * 64 + tid] = accS;
        float p = el[tid] * el[tid] + el[tid + 64] * el[tid + 64];
#pragma unroll
        for (int o = 32; o > 0; o >>= 1) p += __shfl_down(p, o);
        if (tid == 0) e2part[b] = p;
    }
    __threadfence();
    grid.sync();

    // ---- phase 2 ----
    {
        const int j = tid & 63, g = tid >> 6;
        float p = 0.f;
        for (int bb = g * 16; bb < g * 16 + 16; ++bb)
            p += Gpart[(bb * 64 + b) * 64 + j];
        r4a[g][j] = p;
    }
    __syncthreads();
    if (tid < 64)
        Grow[tid] = r4a[0][tid] + r4a[1][tid] + r4a[2][tid] + r4a[3][tid];
    __syncthreads();
    if (tid < 64) {
        const int p = tid;
        float acc = 0.f;
#pragma unroll 8
        for (int j = 0; j < 64; ++j) acc += Grow[j] * Fs[p][j];
        Mg[b * 64 + p] = acc * (1.0f / 64.0f);
    }
    if (b == 0 && tid < 64) {
        float s = 0.f;
        for (int bb = 0; bb < 64; ++bb) s += spart[bb * 64 + tid];
        sred[tid] = s;
    }
    if (b == 1 && tid < 64) { Ag[tid] = 0.f; Bg[tid] = 0.f; bMg[tid] = 0.f; }
    if (b == 2 && tid == 0) {
        float e = 0.f;
        for (int bb = 0; bb < 64; ++bb) e += e2part[bb];
        E2g[0] = e;
    }
    __threadfence();
    grid.sync();

    // ---- phase 3 ----
    for (int i = tid; i < 4096; i += 256)
        Msh[i >> 6][i & 63] = Mg[i];
    __syncthreads();
    if (tid < 64) {
        const int p = tid;
        float gm = 0.f;
#pragma unroll 8
        for (int kk = 0; kk < 64; ++kk) gm += Grow[kk] * Msh[kk][p];
        float mkp = Msh[b][p];
        atomicAdd(&Ag[p],  mkp * gm);
        atomicAdd(&Bg[p],  sred[b] * mkp);
        atomicAdd(&bMg[p], bn1b[b] * mkp);
    }
    if (b == 0 && tid < 64) {
        const int p = tid;
        float sv = 0.f;
#pragma unroll 8
        for (int j = 0; j < 64; ++j) sv += sred[j] * Fs[p][j];
        svg[p] = sv;
    }
    __threadfence();
    grid.sync();

    // ---- phase 4 ----
    if (tid < 64) {
        const int p = tid;
        float bsum = 0.f;
        for (int j = 0; j < 64; ++j) bsum += bn1b[j];
        float Esum = (float)N_ROWS * bsum * (1.0f / 64.0f);
        float svp = svg[p];
        float Su  = (float)N_ROWS * bMg[p] - Esum * svp;
        float Su2 = Ag[p] - 2.0f * svp * Bg[p] + E2g[0] * svp * svp;
        float f = fcb[p];
        float cs = Su + (float)N_ROWS * f;
        float cq = Su2 + 2.0f * f * Su + (float)N_ROWS * f * f;
        float m2 = cs * (1.0f / N_ROWS);
        float v2 = cq * (1.0f / N_ROWS) - m2 * m2;
        float a = bn2w[p] * rsqrtf(v2 + 1e-5f);
        a2s[p] = a; c2s[p] = bn2b[p] - m2 * a;
        svs[p] = svp; fcs[p] = f; wos[p] = fow[p];
    }
    __syncthreads();
    const float bo = fob[0];
#pragma unroll 1
    for (int pass = 0; pass < 4; ++pass) {
        const int row = pass * 32 + (tid >> 3);
        const int pg = (tid & 7) << 3;
        float acc[8];
#pragma unroll
        for (int i = 0; i < 8; ++i) acc[i] = 0.f;
#pragma unroll 4
        for (int k = 0; k < 64; ++k) {
            float hv = tile[row][k];
#pragma unroll
            for (int i = 0; i < 8; ++i) acc[i] += hv * Msh[k][pg + i];
        }
        const float ev = el[row];
        float part = 0.f;
#pragma unroll
        for (int i = 0; i < 8; ++i) {
            int p = pg + i;
            float v = acc[i] - ev * svs[p] + fcs[p];
            v = v * a2s[p] + c2s[p];
            v = (v >= 0.f) ? v : 0.01f * v;
            part += v * wos[p];
        }
        part += __shfl_xor(part, 1);
        part += __shfl_xor(part, 2);
        part += __shfl_xor(part, 4);
        if ((tid & 7) == 0) y[b * 128 + row] = part + bo;
    }
}

extern "C" void kernel_launch(void* const* d_in, const int* in_sizes, int n_in,
                              void* d_out, int out_size, void* d_ws, size_t ws_size,
                              hipStream_t stream)
{
    const float* x    = (const float*)d_in[0];
    const float* Wih0 = (const float*)d_in[1];
    const float* Whh0 = (const float*)d_in[2];
    const float* bih0 = (const float*)d_in[3];
    const float* bhh0 = (const float*)d_in[4];
    const float* Wih1 = (const float*)d_in[5];
    const float* Whh1 = (const float*)d_in[6];
    const float* bih1 = (const float*)d_in[7];
    const float* bhh1 = (const float*)d_in[8];
    const float* bn1w = (const float*)d_in[9];
    const float* bn1b = (const float*)d_in[10];
    const float* fcw  = (const float*)d_in[11];
    const float* fcb  = (const float*)d_in[12];
    const float* bn2w = (const float*)d_in[13];
    const float* bn2b = (const float*)d_in[14];
    const float* fow  = (const float*)d_in[15];
    const float* fob  = (const float*)d_in[16];
    float* y = (float*)d_out;

    float* ws = (float*)d_ws;
    float* hidden = ws;                  // 8192*64
    float* wsb    = ws + 524288;         // tail workspace (~280k floats)

    gru_fused<<<512, 512, 0, stream>>>(x, Wih0, Whh0, bih0, bhh0,
                                       Wih1, Whh1, bih1, bhh1, hidden);

    void* args[] = {(void*)&hidden, (void*)&bn1w, (void*)&bn1b, (void*)&fcw,
                    (void*)&fcb, (void*)&bn2w, (void*)&bn2b, (void*)&fow,
                    (void*)&fob, (void*)&y, (void*)&wsb};
    hipLaunchCooperativeKernel((void*)tail_kernel, dim3(64), dim3(256),
                               args, 0, stream);
}

// Round 8
// 232.476 us; speedup vs baseline: 1.2162x; 1.2162x over previous
//
#include <hip/hip_runtime.h>
#include <hip/hip_bf16.h>

#define N_ROWS 8192
#define T_STEPS 60
#define DFEAT 6

typedef _Float16 f16x8 __attribute__((ext_vector_type(8)));
typedef float f32x4 __attribute__((ext_vector_type(4)));
typedef float fvec4 __attribute__((ext_vector_type(4)));

#if __has_builtin(__builtin_amdgcn_exp2f)
#define EXP2F(x) __builtin_amdgcn_exp2f(x)
#else
#define EXP2F(x) exp2f(x)
#endif
#define RCPF(x) __builtin_amdgcn_rcpf(x)

#define LOG2E  1.4426950408889634f
#define LOG2E2 2.8853900817779268f

#define MFMA16(a, b, c) __builtin_amdgcn_mfma_f32_16x16x32_f16(a, b, c, 0, 0, 0)

#define LOAD_WS(W, g, kf, SC, DST) do {                                       \
    const float* _p = (W) + ((g)*64 + jcol)*64 + (kf)*32 + rowgrp*8;          \
    fvec4 _v0 = *(const fvec4*)_p;                                            \
    fvec4 _v1 = *(const fvec4*)(_p + 4);                                      \
    f16x8 _f;                                                                 \
    _Pragma("unroll")                                                         \
    for (int _e = 0; _e < 4; ++_e) {                                          \
        _f[_e]     = (_Float16)(_v0[_e] * (SC));                              \
        _f[4 + _e] = (_Float16)(_v1[_e] * (SC));                              \
    }                                                                         \
    DST = _f;                                                                 \
} while (0)

__device__ __forceinline__ int hswz(int row, int col) {
    return row * 64 + (col ^ ((row & 7) << 3));
}

// Persistent MFMA GRU, layer-pipelined across wave roles (as round 6).
// 512 blocks x 512 threads. Waves 0-3: layer 0 step tt; waves 4-7: layer 1
// step tt-1. 1 barrier/step. Weights fp16 in regs pre-scaled by log2e.
// Epilogue: writes hidden (row-major fp16) and hiddenT (col-major fp16).
// No atomics -> no memset node needed.
__global__ __launch_bounds__(512, 4)
void gru_fused(const float* __restrict__ x,
               const float* __restrict__ Wih0, const float* __restrict__ Whh0,
               const float* __restrict__ bih0, const float* __restrict__ bhh0,
               const float* __restrict__ Wih1, const float* __restrict__ Whh1,
               const float* __restrict__ bih1, const float* __restrict__ bhh1,
               _Float16* __restrict__ hidden, _Float16* __restrict__ hiddenT)
{
    __shared__ __align__(16) _Float16 h0s[2][1024];
    __shared__ __align__(16) _Float16 h1s[2][1024];
    __shared__ __align__(16) _Float16 xs[T_STEPS][16][8];
    __shared__ __align__(16) _Float16 zx[8];

    const int tid = threadIdx.x;
    const int lane = tid & 63;
    const int wv = tid >> 6;
    const int roleB = wv >> 2;
    const int cg_ = wv & 3;
    const int lrow = lane & 15;
    const int rowgrp = lane >> 4;
    const int jcol = cg_ * 16 + lrow;
    const int rbase = blockIdx.x * 16;

    for (int i = tid; i < 1024; i += 512) {
        h0s[0][i] = (_Float16)0.f; h0s[1][i] = (_Float16)0.f;
        h1s[0][i] = (_Float16)0.f; h1s[1][i] = (_Float16)0.f;
    }
    if (tid < 8) zx[tid] = (_Float16)0.f;
    for (int idx = tid; idx < 16 * T_STEPS; idx += 512) {
        int t = idx >> 4, r = idx & 15;
        const float* xp = x + (long)(rbase + r) * (DFEAT * T_STEPS) + t;
        f16x8 f;
#pragma unroll
        for (int d = 0; d < DFEAT; ++d) f[d] = (_Float16)xp[d * T_STEPS];
        f[6] = (_Float16)0.f; f[7] = (_Float16)0.f;
        *(f16x8*)&xs[t][r][0] = f;
    }

    f16x8 zerof;
#pragma unroll
    for (int e = 0; e < 8; ++e) zerof[e] = (_Float16)0.f;

    f16x8 wg[12];
#pragma unroll
    for (int i = 0; i < 12; ++i) wg[i] = zerof;
    float br, bz, bxn, bhn;
    if (roleB == 0) {
        LOAD_WS(Whh0, 0, 0, LOG2E,  wg[0]);  LOAD_WS(Whh0, 0, 1, LOG2E,  wg[1]);
        LOAD_WS(Whh0, 1, 0, LOG2E,  wg[2]);  LOAD_WS(Whh0, 1, 1, LOG2E,  wg[3]);
        LOAD_WS(Whh0, 2, 0, LOG2E2, wg[4]);  LOAD_WS(Whh0, 2, 1, LOG2E2, wg[5]);
        if (rowgrp == 0) {
#pragma unroll
            for (int g = 0; g < 3; ++g) {
                const float sc = (g == 2) ? LOG2E2 : LOG2E;
                f16x8 f = zerof;
#pragma unroll
                for (int e = 0; e < DFEAT; ++e)
                    f[e] = (_Float16)(Wih0[(g * 64 + jcol) * DFEAT + e] * sc);
                wg[6 + g] = f;
            }
        }
        br  = (bih0[jcol] + bhh0[jcol]) * LOG2E;
        bz  = (bih0[64 + jcol] + bhh0[64 + jcol]) * LOG2E;
        bxn = bih0[128 + jcol] * LOG2E2;
        bhn = bhh0[128 + jcol] * LOG2E2;
    } else {
        LOAD_WS(Wih1, 0, 0, LOG2E,  wg[0]);  LOAD_WS(Wih1, 0, 1, LOG2E,  wg[1]);
        LOAD_WS(Wih1, 1, 0, LOG2E,  wg[2]);  LOAD_WS(Wih1, 1, 1, LOG2E,  wg[3]);
        LOAD_WS(Wih1, 2, 0, LOG2E2, wg[4]);  LOAD_WS(Wih1, 2, 1, LOG2E2, wg[5]);
        LOAD_WS(Whh1, 0, 0, LOG2E,  wg[6]);  LOAD_WS(Whh1, 0, 1, LOG2E,  wg[7]);
        LOAD_WS(Whh1, 1, 0, LOG2E,  wg[8]);  LOAD_WS(Whh1, 1, 1, LOG2E,  wg[9]);
        LOAD_WS(Whh1, 2, 0, LOG2E2, wg[10]); LOAD_WS(Whh1, 2, 1, LOG2E2, wg[11]);
        br  = (bih1[jcol] + bhh1[jcol]) * LOG2E;
        bz  = (bih1[64 + jcol] + bhh1[64 + jcol]) * LOG2E;
        bxn = bih1[128 + jcol] * LOG2E2;
        bhn = bhh1[128 + jcol] * LOG2E2;
    }

    float hreg[4] = {0.f, 0.f, 0.f, 0.f};

    const _Float16* xbase_l = (rowgrp == 0) ? &xs[0][lrow][0] : &zx[0];
    const long xinc = (rowgrp == 0) ? 128 : 0;

    int widx[4];
#pragma unroll
    for (int q = 0; q < 4; ++q) widx[q] = hswz(rowgrp * 4 + q, jcol);
    const int ridx0 = lrow * 64 + ((rowgrp * 8) ^ ((lrow & 7) << 3));
    const int ridx1 = lrow * 64 + ((32 + rowgrp * 8) ^ ((lrow & 7) << 3));

    __syncthreads();

#pragma unroll 1
    for (int tt = 0; tt <= T_STEPS; ++tt) {
        if (roleB == 0) {
            if (tt < T_STEPS) {
                const int rb = (tt + 1) & 1;
                f16x8 hf0 = *(const f16x8*)&h0s[rb][ridx0];
                f16x8 hf1 = *(const f16x8*)&h0s[rb][ridx1];
                f16x8 xf  = *(const f16x8*)(xbase_l + (long)tt * xinc);
                f32x4 accr  = {br, br, br, br};
                f32x4 accz  = {bz, bz, bz, bz};
                f32x4 accxn = {bxn, bxn, bxn, bxn};
                f32x4 acchn = {bhn, bhn, bhn, bhn};
                accr  = MFMA16(xf,  wg[6], accr);
                accr  = MFMA16(hf0, wg[0], accr);
                accr  = MFMA16(hf1, wg[1], accr);
                accz  = MFMA16(xf,  wg[7], accz);
                accz  = MFMA16(hf0, wg[2], accz);
                accz  = MFMA16(hf1, wg[3], accz);
                accxn = MFMA16(xf,  wg[8], accxn);
                acchn = MFMA16(hf0, wg[4], acchn);
                acchn = MFMA16(hf1, wg[5], acchn);
#pragma unroll
                for (int q = 0; q < 4; ++q) {
                    float r = RCPF(1.0f + EXP2F(-accr[q]));
                    float z = RCPF(1.0f + EXP2F(-accz[q]));
                    float v = accxn[q] + r * acchn[q];
                    float n = 2.0f * RCPF(1.0f + EXP2F(-v)) - 1.0f;
                    hreg[q] = n + z * (hreg[q] - n);
                }
                const int wb = tt & 1;
#pragma unroll
                for (int q = 0; q < 4; ++q)
                    h0s[wb][widx[q]] = (_Float16)hreg[q];
            }
        } else {
            if (tt > 0) {
                const int rb0 = (tt + 1) & 1;
                const int rb1 = tt & 1;
                f16x8 xf0 = *(const f16x8*)&h0s[rb0][ridx0];
                f16x8 xf1 = *(const f16x8*)&h0s[rb0][ridx1];
                f16x8 hf0 = *(const f16x8*)&h1s[rb1][ridx0];
                f16x8 hf1 = *(const f16x8*)&h1s[rb1][ridx1];
                f32x4 accr  = {br, br, br, br};
                f32x4 accz  = {bz, bz, bz, bz};
                f32x4 accxn = {bxn, bxn, bxn, bxn};
                f32x4 acchn = {bhn, bhn, bhn, bhn};
                accr  = MFMA16(xf0, wg[0], accr);
                accr  = MFMA16(xf1, wg[1], accr);
                accr  = MFMA16(hf0, wg[6], accr);
                accr  = MFMA16(hf1, wg[7], accr);
                accz  = MFMA16(xf0, wg[2], accz);
                accz  = MFMA16(xf1, wg[3], accz);
                accz  = MFMA16(hf0, wg[8], accz);
                accz  = MFMA16(hf1, wg[9], accz);
                accxn = MFMA16(xf0, wg[4], accxn);
                accxn = MFMA16(xf1, wg[5], accxn);
                acchn = MFMA16(hf0, wg[10], acchn);
                acchn = MFMA16(hf1, wg[11], acchn);
#pragma unroll
                for (int q = 0; q < 4; ++q) {
                    float r = RCPF(1.0f + EXP2F(-accr[q]));
                    float z = RCPF(1.0f + EXP2F(-accz[q]));
                    float v = accxn[q] + r * acchn[q];
                    float n = 2.0f * RCPF(1.0f + EXP2F(-v)) - 1.0f;
                    hreg[q] = n + z * (hreg[q] - n);
                }
                const int wb = (tt + 1) & 1;
#pragma unroll
                for (int q = 0; q < 4; ++q)
                    h1s[wb][widx[q]] = (_Float16)hreg[q];
            }
        }
        __syncthreads();
    }

    if (roleB == 1) {
#pragma unroll
        for (int q = 0; q < 4; ++q) {
            const int row = rbase + rowgrp * 4 + q;
            _Float16 hv = (_Float16)hreg[q];
            hidden[(long)row * 64 + jcol] = hv;
            hiddenT[(long)jcol * N_ROWS + row] = hv;
        }
    }
}

// Graw = H^T H (64x64) + colsum via a synthesized ones-row tile.
// 24 blocks (r=0..5, c=0..3) x 256 thr (4 waves, K split 4x2048).
// r=4 and r=5 both compute the ones-row (colsum) redundantly with identical
// values -> still effectively single-writer.  No atomics, no memset.
__global__ __launch_bounds__(256)
void gram_kernel(const _Float16* __restrict__ hiddenT,
                 float* __restrict__ Graw, float* __restrict__ colsum)
{
    __shared__ float red[3][64][4];
    const int tid = threadIdx.x;
    const int wv = tid >> 6, lane = tid & 63;
    const int lrow = lane & 15, rg = lane >> 4;
    const int r = blockIdx.x >> 2, c = blockIdx.x & 3;

    const _Float16* pb = hiddenT + (long)(c * 16 + lrow) * N_ROWS + wv * 2048 + rg * 8;
    f32x4 acc[4];
#pragma unroll
    for (int i = 0; i < 4; ++i) acc[i] = (f32x4){0.f, 0.f, 0.f, 0.f};

    if (r < 4) {
        const _Float16* pa = hiddenT + (long)(r * 16 + lrow) * N_ROWS + wv * 2048 + rg * 8;
#pragma unroll 4
        for (int kf = 0; kf < 64; ++kf) {
            f16x8 af = *(const f16x8*)(pa + kf * 32);
            f16x8 bf = *(const f16x8*)(pb + kf * 32);
            acc[kf & 3] = MFMA16(af, bf, acc[kf & 3]);
        }
    } else {
        f16x8 af;
#pragma unroll
        for (int e = 0; e < 8; ++e) af[e] = (lrow == 0) ? (_Float16)1.f : (_Float16)0.f;
#pragma unroll 4
        for (int kf = 0; kf < 64; ++kf) {
            f16x8 bf = *(const f16x8*)(pb + kf * 32);
            acc[kf & 3] = MFMA16(af, bf, acc[kf & 3]);
        }
    }
    f32x4 a0 = acc[0] + acc[1] + acc[2] + acc[3];

    if (wv > 0) {
#pragma unroll
        for (int q = 0; q < 4; ++q) red[wv - 1][lane][q] = a0[q];
    }
    __syncthreads();
    if (wv == 0) {
#pragma unroll
        for (int q = 0; q < 4; ++q)
            a0[q] += red[0][lane][q] + red[1][lane][q] + red[2][lane][q];
        if (r < 4) {
#pragma unroll
            for (int q = 0; q < 4; ++q)
                Graw[(r * 16 + rg * 4 + q) * 64 + c * 16 + lrow] = a0[q];
        } else if (rg == 0) {
            colsum[c * 16 + lrow] = a0[0];   // sum_n H[n][k]
        }
    }
}

// Full tail per block (redundant across 64 blocks; ~1 us each) + 128 rows of y.
// All BN1/BN2 stats derived analytically from Graw/colsum (fp32, exact algebra).
__global__ __launch_bounds__(256)
void final_kernel(const _Float16* __restrict__ hidden,
                  const float* __restrict__ Graw, const float* __restrict__ colsum,
                  const float* __restrict__ bn1w, const float* __restrict__ bn1b,
                  const float* __restrict__ fcw,  const float* __restrict__ fcb,
                  const float* __restrict__ bn2w, const float* __restrict__ bn2b,
                  const float* __restrict__ fow,  const float* __restrict__ fob,
                  float* __restrict__ y)
{
    __shared__ float Gbn[64][65];
    __shared__ float Ms[64][65];
    __shared__ _Float16 tile[128][72];
    __shared__ float el[128];
    __shared__ float a1s[64], c1s[64], S1s[64], S1bn[64], s_s[64];
    __shared__ float svs[64], a2s[64], c2s[64], fcs[64], wos[64];
    __shared__ float red[4][64];
    __shared__ float E2s, Esums;

    const int b = blockIdx.x, tid = threadIdx.x;
    const float Nf = (float)N_ROWS;

    if (tid < 64) {
        float S1 = colsum[tid];
        S1s[tid] = S1;
        float m = S1 * (1.0f / Nf);
        float var = Graw[tid * 65] * (1.0f / Nf) - m * m;   // diag = colsumsq
        float a = bn1w[tid] * rsqrtf(var + 1e-5f);
        float cc = bn1b[tid] - m * a;
        a1s[tid] = a; c1s[tid] = cc;
        S1bn[tid] = a * S1 + Nf * cc;
    }
    __syncthreads();

    // Gbn[j][k] = a_j a_k G + a_j c_k S1_j + c_j a_k S1_k + N c_j c_k
    for (int i = tid; i < 4096; i += 256) {
        int j = i >> 6, k = i & 63;
        Gbn[j][k] = a1s[j] * a1s[k] * Graw[i]
                  + a1s[j] * c1s[k] * S1s[j]
                  + c1s[j] * a1s[k] * S1s[k]
                  + Nf * c1s[j] * c1s[k];
    }
    __syncthreads();

    // s_k = (1/64) sum_j Gbn[j][k]
    {
        const int k = tid & 63, g = tid >> 6;
        float p = 0.f;
        for (int j = g * 16; j < g * 16 + 16; ++j) p += Gbn[j][k];
        red[g][k] = p;
    }
    __syncthreads();
    if (tid < 64)
        s_s[tid] = (red[0][tid] + red[1][tid] + red[2][tid] + red[3][tid]) * (1.0f / 64.0f);
    __syncthreads();
    if (tid == 0) {
        float e2 = 0.f, es = 0.f;
        for (int k = 0; k < 64; ++k) { e2 += s_s[k]; es += S1bn[k]; }
        E2s = e2 * (1.0f / 64.0f);        // sum_n e^2
        Esums = es * (1.0f / 64.0f);      // sum_n e
    }

    // M[k][p] = (1/64) sum_j Gbn[k][j] fcw[p][j]
    for (int i = tid; i < 4096; i += 256) {
        int k = i >> 6, p = i & 63;
        float acc = 0.f;
#pragma unroll 8
        for (int j = 0; j < 64; ++j) acc += Gbn[k][j] * fcw[p * 64 + j];
        Ms[k][p] = acc * (1.0f / 64.0f);
    }
    __syncthreads();

    // A_p = (M^T Gbn M)[p,p], partial over j-quarters
    {
        const int p = tid & 63, g = tid >> 6;
        float pa = 0.f;
        for (int j = g * 16; j < g * 16 + 16; ++j) {
            float gm = 0.f;
#pragma unroll 8
            for (int k = 0; k < 64; ++k) gm += Gbn[j][k] * Ms[k][p];
            pa += Ms[j][p] * gm;
        }
        red[g][p] = pa;
    }
    __syncthreads();

    if (tid < 64) {
        const int p = tid;
        float A = red[0][p] + red[1][p] + red[2][p] + red[3][p];
        float sv = 0.f, B = 0.f, SuS = 0.f;
#pragma unroll 8
        for (int j = 0; j < 64; ++j) {
            sv  += s_s[j] * fcw[p * 64 + j];
            B   += s_s[j] * Ms[j][p];
            SuS += S1bn[j] * Ms[j][p];
        }
        float Su  = SuS - Esums * sv;
        float Su2 = A - 2.0f * sv * B + E2s * sv * sv;
        float f = fcb[p];
        float cs = Su + Nf * f;
        float cq = Su2 + 2.0f * f * Su + Nf * f * f;
        float m2 = cs * (1.0f / Nf);
        float v2 = cq * (1.0f / Nf) - m2 * m2;
        float a = bn2w[p] * rsqrtf(v2 + 1e-5f);
        a2s[p] = a; c2s[p] = bn2b[p] - m2 * a;
        svs[p] = sv; fcs[p] = f; wos[p] = fow[p];
    }
    __syncthreads();

    // hbn tile (fp16) + row means
    for (int i = tid; i < 128 * 64; i += 256) {
        int r = i >> 6, cc = i & 63;
        float hv = (float)hidden[(long)(b * 128 + r) * 64 + cc];
        tile[r][cc] = (_Float16)(hv * a1s[cc] + c1s[cc]);
    }
    __syncthreads();
    for (int r = tid; r < 128; r += 256) {
        float s = 0.f;
#pragma unroll 8
        for (int cc = 0; cc < 64; ++cc) s += (float)tile[r][cc];
        el[r] = s * (1.0f / 64.0f);
    }
    __syncthreads();

    const float bo = fob[0];
#pragma unroll 1
    for (int pass = 0; pass < 4; ++pass) {
        const int row = pass * 32 + (tid >> 3);
        const int pg = (tid & 7) << 3;
        float acc[8];
#pragma unroll
        for (int i = 0; i < 8; ++i) acc[i] = 0.f;
#pragma unroll 4
        for (int k = 0; k < 64; ++k) {
            float hv = (float)tile[row][k];
#pragma unroll
            for (int i = 0; i < 8; ++i) acc[i] += hv * Ms[k][pg + i];
        }
        const float ev = el[row];
        float part = 0.f;
#pragma unroll
        for (int i = 0; i < 8; ++i) {
            int p = pg + i;
            float v = acc[i] - ev * svs[p] + fcs[p];
            v = v * a2s[p] + c2s[p];
            v = (v >= 0.f) ? v : 0.01f * v;
            part += v * wos[p];
        }
        part += __shfl_xor(part, 1);
        part += __shfl_xor(part, 2);
        part += __shfl_xor(part, 4);
        if ((tid & 7) == 0) y[b * 128 + row] = part + bo;
    }
}

extern "C" void kernel_launch(void* const* d_in, const int* in_sizes, int n_in,
                              void* d_out, int out_size, void* d_ws, size_t ws_size,
                              hipStream_t stream)
{
    const float* x    = (const float*)d_in[0];
    const float* Wih0 = (const float*)d_in[1];
    const float* Whh0 = (const float*)d_in[2];
    const float* bih0 = (const float*)d_in[3];
    const float* bhh0 = (const float*)d_in[4];
    const float* Wih1 = (const float*)d_in[5];
    const float* Whh1 = (const float*)d_in[6];
    const float* bih1 = (const float*)d_in[7];
    const float* bhh1 = (const float*)d_in[8];
    const float* bn1w = (const float*)d_in[9];
    const float* bn1b = (const float*)d_in[10];
    const float* fcw  = (const float*)d_in[11];
    const float* fcb  = (const float*)d_in[12];
    const float* bn2w = (const float*)d_in[13];
    const float* bn2b = (const float*)d_in[14];
    const float* fow  = (const float*)d_in[15];
    const float* fob  = (const float*)d_in[16];
    float* y = (float*)d_out;

    _Float16* hidden  = (_Float16*)d_ws;             // 8192*64 fp16 (1 MB)
    _Float16* hiddenT = hidden + 524288;             // 64*8192 fp16 (1 MB)
    float* Graw   = (float*)(hidden + 1048576);      // 4096
    float* colsum = Graw + 4096;                     // 64

    gru_fused<<<512, 512, 0, stream>>>(x, Wih0, Whh0, bih0, bhh0,
                                       Wih1, Whh1, bih1, bhh1,
                                       hidden, hiddenT);
    gram_kernel<<<24, 256, 0, stream>>>(hiddenT, Graw, colsum);
    final_kernel<<<64, 256, 0, stream>>>(hidden, Graw, colsum, bn1w, bn1b,
                                         fcw, fcb, bn2w, bn2b, fow, fob, y);
}